// Round 1
// baseline (4605.244 us; speedup 1.0000x reference)
//
#include <hip/hip_runtime.h>

// CustomRNN: S=2048 steps, B=64, I=256, H=512, E=256.
//   m_t = h_{t-1} @ We.T + be ;  h_t = tanh([x_t, m_{t-1}] @ Wih.T + bih)
// Rewrite: h_t = tanh(x_t@Wx.T + bih + be@Wm.T + h_{t-2}@W2),  W2 = We.T@Wm.T
//  -> two independent parity chains, 1024 sequential supersteps.
// 8 groups (8 batch rows each) x 8 member-WGs (64-col slice each), 256 thr/WG.
// W2/Wx fragments live in VGPRs (pre-swizzled by prep kernel). Cross-WG
// exchange of h slices through a device-scope published buffer + counter.

#define S2    1024
#define OUT_HT 67108864          // 2048*64*512
#define OUT_MT 67141632          // + 64*512

typedef _Float16 half8 __attribute__((ext_vector_type(8)));
typedef float f32x4 __attribute__((ext_vector_type(4)));

// ---- workspace layout (bytes) ----
#define OFF_W2F   0u         // 512*512 f16 fragment-ordered  (524288)
#define OFF_WXF   524288u    // 512*256 f16 fragment-ordered  (262144)
#define OFF_C2    786432u    // 512 f32   bih + be@Wm.T
#define OFF_AVE   788480u    // 64*512 f32  bih + m0@Wm.T          (t=0 addvec)
#define OFF_AVO   919552u    // 64*512 f32  bih + (h0@We.T+be)@Wm.T (t=1 addvec)
#define OFF_MEMB  1050624u   // 64*256 f32  h0@We.T+be
#define OFF_HX    1116160u   // 2*8*16*512 f16 exchange (262144)
#define OFF_CNT   1378304u   // 64 u32 counters

// ---------------- prep 1: memb = h0@We.T + be ----------------
__global__ __launch_bounds__(256) void k_memb(const float* __restrict__ h0,
                                              const float* __restrict__ We,
                                              const float* __restrict__ be,
                                              float* __restrict__ memb) {
  __shared__ float hs[512];
  int b = blockIdx.x, e = threadIdx.x;
  for (int i = threadIdx.x; i < 512; i += 256) hs[i] = h0[b * 512 + i];
  __syncthreads();
  float acc = be[e];
  const float* wr = We + (size_t)e * 512;
  for (int h = 0; h < 512; ++h) acc += hs[h] * wr[h];
  memb[b * 256 + e] = acc;
}

// ---------------- prep 2: weights->fragments, addvecs, counters ----------------
__global__ __launch_bounds__(256) void k_prep(
    const float* __restrict__ We, const float* __restrict__ be,
    const float* __restrict__ Wih, const float* __restrict__ bih,
    const float* __restrict__ m0, const float* __restrict__ memb,
    _Float16* __restrict__ w2f, _Float16* __restrict__ wxf,
    float* __restrict__ c2, float* __restrict__ ave, float* __restrict__ avo,
    unsigned int* __restrict__ cnt) {
  int blk = blockIdx.x, tid = threadIdx.x;
  if (blk < 1024) {                       // W2[k][n] = sum_e We[e,k]*Wih[n,256+e]
    int idx = blk * 256 + tid;
    int k = idx & 511, n = idx >> 9;
    float acc = 0.f;
    for (int e = 0; e < 256; ++e)
      acc += We[e * 512 + k] * Wih[n * 512 + 256 + e];
    int ntile = n >> 4, nl = n & 15;
    int kch = k >> 5, kq = (k >> 3) & 3, ke = k & 7;
    int lane = kq * 16 + nl;
    w2f[(size_t)((ntile * 16 + kch) * 64 + lane) * 8 + ke] = (_Float16)acc;
  } else if (blk < 1536) {                // Wx[k][n] = Wih[n][k], k<256
    int idx = (blk - 1024) * 256 + tid;
    int k = idx & 255, n = idx >> 8;
    float v = Wih[n * 512 + k];
    int ntile = n >> 4, nl = n & 15;
    int kch = k >> 5, kq = (k >> 3) & 3, ke = k & 7;
    int lane = kq * 16 + nl;
    wxf[(size_t)((ntile * 8 + kch) * 64 + lane) * 8 + ke] = (_Float16)v;
  } else if (blk < 1538) {                // c2 = bih + be@Wm.T
    int j = (blk - 1536) * 256 + tid;
    float acc = bih[j];
    for (int e = 0; e < 256; ++e) acc += be[e] * Wih[j * 512 + 256 + e];
    c2[j] = acc;
  } else if (blk < 1666) {                // ave = bih + m0@Wm.T
    int i = blk - 1538;
    int b = i >> 1, j = (i & 1) * 256 + tid;
    float acc = bih[j];
    for (int e = 0; e < 256; ++e) acc += m0[b * 256 + e] * Wih[j * 512 + 256 + e];
    ave[b * 512 + j] = acc;
  } else if (blk < 1794) {                // avo = bih + memb@Wm.T
    int i = blk - 1666;
    int b = i >> 1, j = (i & 1) * 256 + tid;
    float acc = bih[j];
    for (int e = 0; e < 256; ++e) acc += memb[b * 256 + e] * Wih[j * 512 + 256 + e];
    avo[b * 512 + j] = acc;
  } else {
    if (tid < 64) cnt[tid] = 0u;
  }
}

__device__ inline float fast_tanh(float x) {
  float z = __expf(2.f * x);
  return 1.f - 2.f / (z + 1.f);          // saturates correctly at +-1
}

// ---------------- main sequential kernel ----------------
__global__ __launch_bounds__(256, 1) void k_main(
    const float* __restrict__ x,
    const _Float16* __restrict__ w2f, const _Float16* __restrict__ wxf,
    const float* __restrict__ c2, const float* __restrict__ ave,
    const float* __restrict__ avo, _Float16* __restrict__ hx,
    unsigned int* __restrict__ cnt, float* __restrict__ out) {
  // LDS staging only; weights live in VGPRs. Row strides padded: bank = 4*(m+q)%32 -> 2-way (free).
  __shared__ __align__(16) _Float16 ha[16 * 520];       // h_prev (16 chains x 512)
  __shared__ __align__(16) _Float16 xl[2][16 * 264];    // x double buffer (16 rows x 256)

  const int tid = threadIdx.x;
  const int g = blockIdx.x & 7;          // group: blockIdx%8 -> same XCD (heuristic)
  const int w = blockIdx.x >> 3;         // member 0..7, owns cols [w*64, w*64+64)
  const int wave = tid >> 6, lane = tid & 63;
  const int q = lane >> 4, nl = lane & 15;
  const int ntile = w * 4 + wave;
  const int j = (ntile << 4) + nl;       // global output column

  // --- load permanent weight fragments into registers ---
  half8 w2r[16];
#pragma unroll
  for (int kc = 0; kc < 16; ++kc)
    w2r[kc] = *(const half8*)(w2f + (size_t)((ntile * 16 + kc) * 64 + lane) * 8);
  half8 wxr[8];
#pragma unroll
  for (int kc = 0; kc < 8; ++kc)
    wxr[kc] = *(const half8*)(wxf + (size_t)((ntile * 8 + kc) * 64 + lane) * 8);

  const float c2l = c2[j];
  float av0[4];
#pragma unroll
  for (int r = 0; r < 4; ++r) {
    int m = q * 4 + r;
    av0[r] = (m < 8) ? ave[(g * 8 + m) * 512 + j] : avo[(g * 8 + (m & 7)) * 512 + j];
  }

  const int row = tid >> 4, seg = tid & 15;
  const int bb = g * 8 + (row & 7);

  // --- stage x for s=0 (t = parity) ---
  {
    int t = (row >> 3);
    const float* xp = x + (size_t)(t * 64 + bb) * 256 + seg * 16;
    _Float16* dst = &xl[0][row * 264 + seg * 16];
#pragma unroll
    for (int i = 0; i < 16; ++i) dst[i] = (_Float16)xp[i];
  }
  __syncthreads();

  for (int s = 0; s < S2; ++s) {
    // 1. prefetch next superstep's x rows into registers (latency hidden)
    float xpre[16];
    if (s + 1 < S2) {
      int t = 2 * (s + 1) + (row >> 3);
      const float* xp = x + (size_t)(t * 64 + bb) * 256 + seg * 16;
#pragma unroll
      for (int i = 0; i < 4; ++i) {
        float4 v = *(const float4*)(xp + i * 4);
        xpre[i * 4 + 0] = v.x; xpre[i * 4 + 1] = v.y;
        xpre[i * 4 + 2] = v.z; xpre[i * 4 + 3] = v.w;
      }
    }

    f32x4 acc = {0.f, 0.f, 0.f, 0.f};

    // 2. chain contribution h_prev @ W2 (skipped at s=0; init folded into av0)
    if (s > 0) {
      if (tid == 0) {
        unsigned target = 8u * (unsigned)s;
        while (__hip_atomic_load(&cnt[g], __ATOMIC_RELAXED, __HIP_MEMORY_SCOPE_AGENT) < target)
          __builtin_amdgcn_s_sleep(1);
        __builtin_amdgcn_fence(__ATOMIC_ACQUIRE, "agent");   // invalidate stale cache
      }
      __syncthreads();
      // stage published h slices (16 chains x 512 f16) into LDS
      const _Float16* src = hx + (size_t)((((s - 1) & 1) * 8 + g) * 16 + row) * 512;
      {
        _Float16* drow = &ha[row * 520];
#pragma unroll
        for (int i = 0; i < 4; ++i) {
          int idx = seg + 16 * i;
          *(float4*)(drow + idx * 8) = *(const float4*)(src + idx * 8);
        }
      }
      __syncthreads();
#pragma unroll
      for (int kc = 0; kc < 16; ++kc) {
        half8 a = *(const half8*)(&ha[nl * 520 + kc * 32 + q * 8]);
        acc = __builtin_amdgcn_mfma_f32_16x16x32_f16(a, w2r[kc], acc, 0, 0, 0);
      }
    }

    // 3. x contribution
#pragma unroll
    for (int kc = 0; kc < 8; ++kc) {
      half8 a = *(const half8*)(&xl[s & 1][nl * 264 + kc * 32 + q * 8]);
      acc = __builtin_amdgcn_mfma_f32_16x16x32_f16(a, wxr[kc], acc, 0, 0, 0);
    }

    // 4. epilogue: bias + tanh, write outputs + exchange slice
#pragma unroll
    for (int r = 0; r < 4; ++r) {
      int m = q * 4 + r;                       // chain: 0..7 even, 8..15 odd
      float pre = acc[r] + (s == 0 ? av0[r] : c2l);
      float h = fast_tanh(pre);
      int t = 2 * s + (m >> 3);
      int b = g * 8 + (m & 7);
      out[(size_t)(t * 64 + b) * 512 + j] = h;
      if (s == S2 - 1 && m >= 8) out[(size_t)OUT_HT + b * 512 + j] = h;
      hx[(size_t)(((s & 1) * 8 + g) * 16 + m) * 512 + j] = (_Float16)h;
    }

    // 5. convert + store prefetched x into the other buffer
    if (s + 1 < S2) {
      _Float16* dst = &xl[(s + 1) & 1][row * 264 + seg * 16];
#pragma unroll
      for (int i = 0; i < 16; ++i) dst[i] = (_Float16)xpre[i];
    }

    // 6. publish (syncthreads drains all stores, then release-add flushes L2)
    __syncthreads();
    if (tid == 0)
      __hip_atomic_fetch_add(&cnt[g], 1u, __ATOMIC_RELEASE, __HIP_MEMORY_SCOPE_AGENT);
  }
}

// ---------------- final m_T = h_2046 @ We.T + be ----------------
__global__ __launch_bounds__(256) void k_mt(float* __restrict__ out,
                                            const float* __restrict__ We,
                                            const float* __restrict__ be) {
  __shared__ float hs[512];
  int b = blockIdx.x, e = threadIdx.x;
  const float* hrow = out + (size_t)(2046 * 64 + b) * 512;
  for (int i = threadIdx.x; i < 512; i += 256) hs[i] = hrow[i];
  __syncthreads();
  float acc = be[e];
  const float* wr = We + (size_t)e * 512;
  for (int h = 0; h < 512; ++h) acc += hs[h] * wr[h];
  out[(size_t)OUT_MT + b * 256 + e] = acc;
}

extern "C" void kernel_launch(void* const* d_in, const int* in_sizes, int n_in,
                              void* d_out, int out_size, void* d_ws, size_t ws_size,
                              hipStream_t stream) {
  const float* x   = (const float*)d_in[0];
  const float* h0  = (const float*)d_in[1];
  const float* m0  = (const float*)d_in[2];
  const float* We  = (const float*)d_in[3];
  const float* be  = (const float*)d_in[4];
  const float* Wih = (const float*)d_in[5];
  const float* bih = (const float*)d_in[6];
  float* out = (float*)d_out;
  char* ws = (char*)d_ws;

  _Float16* w2f = (_Float16*)(ws + OFF_W2F);
  _Float16* wxf = (_Float16*)(ws + OFF_WXF);
  float* c2   = (float*)(ws + OFF_C2);
  float* ave  = (float*)(ws + OFF_AVE);
  float* avo  = (float*)(ws + OFF_AVO);
  float* memb = (float*)(ws + OFF_MEMB);
  _Float16* hx = (_Float16*)(ws + OFF_HX);
  unsigned int* cnt = (unsigned int*)(ws + OFF_CNT);

  k_memb<<<64, 256, 0, stream>>>(h0, We, be, memb);
  k_prep<<<1795, 256, 0, stream>>>(We, be, Wih, bih, m0, memb, w2f, wxf, c2, ave, avo, cnt);
  k_main<<<64, 256, 0, stream>>>(x, w2f, wxf, c2, ave, avo, hx, cnt, out);
  k_mt<<<64, 256, 0, stream>>>(out, We, be);
}